// Round 1
// baseline (286.784 us; speedup 1.0000x reference)
//
#include <hip/hip_runtime.h>
#include <math.h>

// B=2048, L=64. out = sum(kl) + (BETA-1)*mean_i(log_qz_i - log_qz_product_i)
// lp2[i,j,l] = lp/ln2 = a2*d^2 + b2, d = z_i_l - m_j_l, a2 = -0.5/ln2*exp(-lv) < 0
// Single-pass LSE with constant shift BVAL (valid since lp2 <= b2 << BVAL).
// Horner: lp2 - BVAL = fma(fma(z, a2, c1), z, c0'), c1=-2*a2*m, c0'=a2*m^2+b2-BVAL.
//
// This version: 2 launches total.
//  k1_pre : coefficients + kl partials + zero ticket counters.
//  k23    : fused K2 (t2 chunk-LSE) + K3 (per-(i,l) exp2 sums) on grid (8,128),
//           ITILE=16 (halves coefficient L2 re-reads vs ITILE=8), then
//           fence+ticket last-block finalize per i-tile (old K4) and a global
//           last-block final reduce (old K5). All float reduction orders are
//           identical to the 5-kernel version -> bit-identical output.

#define NB 2048
#define NL 64
#define NE (NB * NL)
#define BVAL 12.0f
#define ITILE 16
#define NTILE (NB / ITILE)  // 128

__device__ __forceinline__ float wredsum(float v) {
#pragma unroll
  for (int o = 32; o; o >>= 1) v += __shfl_xor(v, o, 64);
  return v;
}
__device__ __forceinline__ float wredmax(float v) {
#pragma unroll
  for (int o = 32; o; o >>= 1) v = fmaxf(v, __shfl_xor(v, o, 64));
  return v;
}

// K1: packed Horner coeffs (a2,c1,c0') for the K3 path, transposed arrays +
// qc2 for the K2 path, per-block kl partial sums, and ticket-counter zeroing.
__global__ __launch_bounds__(256) void k1_pre(const float* __restrict__ kl,
                                              const float* __restrict__ zm,
                                              const float* __restrict__ zlv,
                                              float4* __restrict__ PK2,
                                              float* __restrict__ A2T,
                                              float* __restrict__ MA2T,
                                              float* __restrict__ QC2,
                                              float* __restrict__ KLP,
                                              int* __restrict__ CNT) {
  const float INVLN2 = 1.4426950408889634f;
  const float LOG2PI = 1.8378770664093453f;
  int tid = threadIdx.x;
  int e = blockIdx.x * 256 + tid;  // < NE
  int j = e >> 6, l = e & 63;
  if (e < NTILE + 1) CNT[e] = 0;  // re-zero tickets every launch (graph replay)
  float lv = zlv[e], m = zm[e];
  float a2 = -0.5f * INVLN2 * __expf(-lv);
  float b2 = -0.5f * INVLN2 * (lv + LOG2PI);
  float c1 = -2.0f * a2 * m;
  float c0 = fmaf(a2 * m, m, b2);  // true a2*m^2 + b2
  PK2[e] = make_float4(a2, c1, c0 - BVAL, 0.0f);
  A2T[l * NB + j] = a2;
  MA2T[l * NB + j] = c1;
  float q = wredsum(c0);  // sum_l (a2 m^2 + b2) for this j (one j per wave)
  if (l == 0) QC2[j] = q;
  float ks = wredsum(kl[e]);
  __shared__ float sk[4];
  if (l == 0) sk[tid >> 6] = ks;
  __syncthreads();
  if (tid == 0) KLP[blockIdx.x] = sk[0] + sk[1] + sk[2] + sk[3];
}

// Fused K2+K3+K4+K5. grid (8 j-chunks, 128 i-tiles), 256 thr.
// K2 phase: thread = one j, 16 i's; dot over l via zsh (wave-uniform rows).
// K3 phase: thread = (wave w, lane l); 64 j's per wave, 16 i's per thread.
// Finalize: 8th block per i-tile does old-K4 for its 16 i's; 128th finalizer
// does old-K5. int atomic tickets only -> deterministic float order.
__global__ __launch_bounds__(256) void k23(const float* __restrict__ zs,
                                           const float* __restrict__ A2T,
                                           const float* __restrict__ MA2T,
                                           const float* __restrict__ QC2,
                                           const float4* __restrict__ PK2,
                                           float* __restrict__ TPM,
                                           float* __restrict__ TPS,
                                           float* __restrict__ SP,
                                           const float* __restrict__ KLP,
                                           float* __restrict__ PERI,
                                           int* __restrict__ CNT,
                                           float* __restrict__ out) {
  int jc = blockIdx.x;       // 0..7
  int it = blockIdx.y;       // 0..127
  int i0 = it * ITILE;
  int tid = threadIdx.x;
  int w = tid >> 6, l = tid & 63;
  int j = jc * 256 + tid;

  __shared__ float zsh[64][ITILE];        // 4 KB, [k][r]
  __shared__ float lm[4][ITILE], ls[4][ITILE];
  __shared__ float lss[4][ITILE][64];     // 16 KB
  __shared__ float sa[4], sb[4];
  __shared__ int bcast;

  for (int idx = tid; idx < 64 * ITILE; idx += 256) {
    int r = idx >> 6, k = idx & 63;
    zsh[k][r] = zs[(i0 + r) * NL + k];  // coalesced global read
  }
  __syncthreads();

  // ---------------- K2 phase ----------------
  float q = QC2[j];
  float accv[ITILE];
#pragma unroll
  for (int r = 0; r < ITILE; ++r) accv[r] = q;
  for (int k = 0; k < 64; ++k) {
    float av = A2T[k * NB + j];
    float mv = MA2T[k * NB + j];
    const float4* z4 = (const float4*)&zsh[k][0];  // wave-uniform -> broadcast
#pragma unroll
    for (int r4 = 0; r4 < ITILE / 4; ++r4) {
      float4 zq = z4[r4];
      float zk[4] = {zq.x, zq.y, zq.z, zq.w};
#pragma unroll
      for (int rr = 0; rr < 4; ++rr) {
        int r = r4 * 4 + rr;
        accv[r] = fmaf(zk[rr] * zk[rr], av, accv[r]);
        accv[r] = fmaf(zk[rr], mv, accv[r]);
      }
    }
  }
  {
    float Mt[ITILE];
#pragma unroll
    for (int r = 0; r < ITILE; ++r) {
      float mx = wredmax(accv[r]);
      if (l == 0) lm[w][r] = mx;
    }
    __syncthreads();
#pragma unroll
    for (int r = 0; r < ITILE; ++r)
      Mt[r] = fmaxf(fmaxf(lm[0][r], lm[1][r]), fmaxf(lm[2][r], lm[3][r]));
#pragma unroll
    for (int r = 0; r < ITILE; ++r) {
      float ss = wredsum(__builtin_amdgcn_exp2f(accv[r] - Mt[r]));
      if (l == 0) ls[w][r] = ss;
    }
    __syncthreads();
    if (tid == 0) {
#pragma unroll
      for (int r = 0; r < ITILE; ++r) {
        TPM[(i0 + r) * 8 + jc] = Mt[r];
        TPS[(i0 + r) * 8 + jc] = ls[0][r] + ls[1][r] + ls[2][r] + ls[3][r];
      }
    }
  }

  // ---------------- K3 phase ----------------
  float zr[ITILE], S[ITILE];
#pragma unroll
  for (int r = 0; r < ITILE; ++r) zr[r] = zs[(i0 + r) * NL + l];
#pragma unroll
  for (int r = 0; r < ITILE; ++r) S[r] = 0.0f;
  const float4* p = PK2 + (size_t)(jc * 256 + w * 64) * NL + l;
#pragma unroll 4
  for (int jj = 0; jj < 64; ++jj) {
    float4 c = p[(size_t)jj * NL];
#pragma unroll
    for (int r = 0; r < ITILE; ++r) {
      float lp2 = fmaf(fmaf(zr[r], c.x, c.y), zr[r], c.z);
      S[r] += __builtin_amdgcn_exp2f(lp2);
    }
  }
  __syncthreads();  // lss region idle since last barrier
#pragma unroll
  for (int r = 0; r < ITILE; ++r) lss[w][r][l] = S[r];
  __syncthreads();
  for (int pp = tid; pp < ITILE * 64; pp += 256) {
    int r = pp >> 6, ll = pp & 63;
    float Sc = lss[0][r][ll] + lss[1][r][ll] + lss[2][r][ll] + lss[3][r][ll];
    SP[((size_t)jc * NB + (i0 + r)) * NL + ll] = Sc;
  }

  // ---------------- ticket: 8th block of this i-tile finalizes (old K4) ----
  __threadfence();  // release our SP/TPM/TPS writes (device scope, cross-XCD)
  __syncthreads();  // all lanes' fences precede the ticket
  if (tid == 0) bcast = atomicAdd(&CNT[it], 1);
  __syncthreads();
  if (bcast != 7) return;
  __threadfence();  // acquire: see the other 7 blocks' SP/TPM/TPS

#pragma unroll
  for (int rr = 0; rr < 4; ++rr) {
    int i = i0 + w * 4 + rr;  // 4 waves x 4 i's
    float Sv = 0.0f;
#pragma unroll
    for (int s = 0; s < 8; ++s) Sv += SP[((size_t)s * NB + i) * NL + l];
    float val = __builtin_amdgcn_logf(Sv);  // log2
    float lqp2 = wredsum(val) + 64.0f * BVAL;
    float tm = (l < 8) ? TPM[i * 8 + l] : -1e30f;
    float ts = (l < 8) ? TPS[i * 8 + l] : 0.0f;
    float Mtt = wredmax(tm);
    float St = wredsum(ts * __builtin_amdgcn_exp2f(tm - Mtt));
    float lqz2 = Mtt + __builtin_amdgcn_logf(St);
    if (l == 0) PERI[i] = lqz2 - lqp2;
  }

  // ---------------- ticket: 128th finalizer does old K5 ----
  __threadfence();
  __syncthreads();
  if (tid == 0) bcast = atomicAdd(&CNT[NTILE], 1);
  __syncthreads();
  if (bcast != NTILE - 1) return;
  __threadfence();

  float a = 0.0f, b = 0.0f;
  for (int x = tid; x < 512; x += 256) a += KLP[x];
  for (int x = tid; x < NB; x += 256) b += PERI[x];
  float ra = wredsum(a), rb = wredsum(b);
  if (l == 0) { sa[w] = ra; sb[w] = rb; }
  __syncthreads();
  if (tid == 0) {
    const float LN2 = 0.6931471805599453f;
    float ka = sa[0] + sa[1] + sa[2] + sa[3];
    float kb = sb[0] + sb[1] + sb[2] + sb[3];
    out[0] = ka + 5.0f * LN2 * kb * (1.0f / (float)NB);
  }
}

extern "C" void kernel_launch(void* const* d_in, const int* in_sizes, int n_in,
                              void* d_out, int out_size, void* d_ws, size_t ws_size,
                              hipStream_t stream) {
  const float* kl = (const float*)d_in[0];
  const float* zm = (const float*)d_in[1];
  const float* zlv = (const float*)d_in[2];
  const float* zs = (const float*)d_in[3];
  float* ws = (float*)d_ws;

  float* PK2 = ws;                  // 4*NE
  float* A2T = PK2 + 4 * NE;        // NE
  float* MA2T = A2T + NE;           // NE
  float* QC2 = MA2T + NE;           // NB
  float* SP = QC2 + NB;             // 8*NE
  float* TPM = SP + 8 * NE;         // NB*8
  float* TPS = TPM + NB * 8;        // NB*8
  float* KLP = TPS + NB * 8;        // 512
  float* PERI = KLP + 512;          // NB
  int* CNT = (int*)(PERI + NB);     // NTILE+1 tickets  (total ~7.3 MB)

  k1_pre<<<NE / 256, 256, 0, stream>>>(kl, zm, zlv, (float4*)PK2, A2T, MA2T,
                                       QC2, KLP, CNT);
  k23<<<dim3(8, NTILE), 256, 0, stream>>>(zs, A2T, MA2T, QC2, (const float4*)PK2,
                                          TPM, TPS, SP, KLP, PERI, CNT,
                                          (float*)d_out);
}

// Round 2
// 130.158 us; speedup vs baseline: 2.2034x; 2.2034x over previous
//
#include <hip/hip_runtime.h>
#include <math.h>

// B=2048, L=64. out = sum(kl) + (BETA-1)*mean_i(log_qz_i - log_qz_product_i)
// lp2[i,j,l] = lp/ln2 = a2*d^2 + b2, d = z_i_l - m_j_l, a2 = -0.5/ln2*exp(-lv) < 0
// Single-pass LSE with constant shift BVAL (valid since lp2 <= b2 << BVAL).
// Horner: lp2 - BVAL = fma(fma(z, a2, c1), z, c0'), c1=-2*a2*m, c0'=a2*m^2+b2-BVAL.
//
// Round-2 structure (revert of the fence/ticket fusion that regressed 2x):
//  - 4 launches: k1 -> k23 -> k4 -> k5 (kernel boundaries provide coherence;
//    no device fences, which invalidated per-XCD L2 mid-kernel in round 1).
//  - k23 = round-0 k2 and k3 bodies concatenated (identical grid (8,256),
//    ITILE=8, same register footprint as round-0 k3 -> no spills).
//  - K3 coefficient stream packed as float2(a2,c1) + float(c0') = 12B/elem
//    instead of float4 = 16B/elem: 25% less L2 traffic on the dominant stream.
//  - All float reduction orders identical to round 0 -> bit-identical output.

#define NB 2048
#define NL 64
#define NE (NB * NL)
#define BVAL 12.0f

__device__ __forceinline__ float wredsum(float v) {
#pragma unroll
  for (int o = 32; o; o >>= 1) v += __shfl_xor(v, o, 64);
  return v;
}
__device__ __forceinline__ float wredmax(float v) {
#pragma unroll
  for (int o = 32; o; o >>= 1) v = fmaxf(v, __shfl_xor(v, o, 64));
  return v;
}

// K1: packed Horner coeffs (a2,c1 | c0') for the K3 path, transposed arrays +
// qc2 for the K2 path, per-block kl partial sums (no atomics).
__global__ __launch_bounds__(256) void k1_pre(const float* __restrict__ kl,
                                              const float* __restrict__ zm,
                                              const float* __restrict__ zlv,
                                              float2* __restrict__ PK2A,
                                              float* __restrict__ PK2B,
                                              float* __restrict__ A2T,
                                              float* __restrict__ MA2T,
                                              float* __restrict__ QC2,
                                              float* __restrict__ KLP) {
  const float INVLN2 = 1.4426950408889634f;
  const float LOG2PI = 1.8378770664093453f;
  int tid = threadIdx.x;
  int e = blockIdx.x * 256 + tid;  // < NE
  int j = e >> 6, l = e & 63;
  float lv = zlv[e], m = zm[e];
  float a2 = -0.5f * INVLN2 * __expf(-lv);
  float b2 = -0.5f * INVLN2 * (lv + LOG2PI);
  float c1 = -2.0f * a2 * m;
  float c0 = fmaf(a2 * m, m, b2);  // true a2*m^2 + b2
  PK2A[e] = make_float2(a2, c1);
  PK2B[e] = c0 - BVAL;
  A2T[l * NB + j] = a2;
  MA2T[l * NB + j] = c1;
  float q = wredsum(c0);  // sum_l (a2 m^2 + b2) for this j (one j per wave)
  if (l == 0) QC2[j] = q;
  float ks = wredsum(kl[e]);
  __shared__ float sk[4];
  if (l == 0) sk[tid >> 6] = ks;
  __syncthreads();
  if (tid == 0) KLP[blockIdx.x] = sk[0] + sk[1] + sk[2] + sk[3];
}

// Fused K2+K3 (independent phases, same grid, no cross-block comm).
// grid (8 j-chunks, 256 i-tiles), 256 thr.
// K2 phase: thread = one j, 8 i's; block LSE over the 256-j chunk.
// K3 phase: thread = (wave w, lane l); 64 j's per wave, 8 i's per thread.
// Note: linear block id = jc + 8*it -> XCD = bid%8 = jc, so each XCD streams
// only its own 256KB jc-chunk of PK2 (perfect L2 locality); keep this mapping.
__global__ __launch_bounds__(256) void k23(const float* __restrict__ zs,
                                           const float* __restrict__ A2T,
                                           const float* __restrict__ MA2T,
                                           const float* __restrict__ QC2,
                                           const float2* __restrict__ PK2A,
                                           const float* __restrict__ PK2B,
                                           float* __restrict__ TPM,
                                           float* __restrict__ TPS,
                                           float* __restrict__ SP) {
  int jc = blockIdx.x;      // 0..7
  int i0 = blockIdx.y * 8;  // i tile base
  int tid = threadIdx.x;
  int w = tid >> 6, l = tid & 63;
  int j = jc * 256 + tid;

  __shared__ float zsh[64][8];  // [k][r]
  if (tid < 128) {
    int k = tid >> 1, r0 = (tid & 1) * 4;
#pragma unroll
    for (int r = 0; r < 4; ++r) zsh[k][r0 + r] = zs[(i0 + r0 + r) * NL + k];
  }
  __syncthreads();

  // ---------------- K2 phase (identical to round-0 k2_t) ----------------
  float accv[8];
  float q = QC2[j];
#pragma unroll
  for (int r = 0; r < 8; ++r) accv[r] = q;
  for (int k = 0; k < 64; ++k) {
    float av = A2T[k * NB + j];
    float mv = MA2T[k * NB + j];
    const float4* z4 = (const float4*)&zsh[k][0];  // wave-uniform -> broadcast
    float4 za = z4[0], zb = z4[1];
    float zk[8] = {za.x, za.y, za.z, za.w, zb.x, zb.y, zb.z, zb.w};
#pragma unroll
    for (int r = 0; r < 8; ++r) {
      accv[r] = fmaf(zk[r] * zk[r], av, accv[r]);
      accv[r] = fmaf(zk[r], mv, accv[r]);
    }
  }
  __shared__ float lm[4][8], ls[4][8];
  float Mt[8];
#pragma unroll
  for (int r = 0; r < 8; ++r) {
    float mx = wredmax(accv[r]);
    if (l == 0) lm[w][r] = mx;
  }
  __syncthreads();
#pragma unroll
  for (int r = 0; r < 8; ++r)
    Mt[r] = fmaxf(fmaxf(lm[0][r], lm[1][r]), fmaxf(lm[2][r], lm[3][r]));
#pragma unroll
  for (int r = 0; r < 8; ++r) {
    float ss = wredsum(__builtin_amdgcn_exp2f(accv[r] - Mt[r]));
    if (l == 0) ls[w][r] = ss;
  }
  __syncthreads();
  if (tid == 0) {
#pragma unroll
    for (int r = 0; r < 8; ++r) {
      TPM[(i0 + r) * 8 + jc] = Mt[r];
      TPS[(i0 + r) * 8 + jc] = ls[0][r] + ls[1][r] + ls[2][r] + ls[3][r];
    }
  }

  // ---------------- K3 phase (identical math, 12B packed coeffs) ---------
  float zr[8];
#pragma unroll
  for (int r = 0; r < 8; ++r) zr[r] = zs[(i0 + r) * NL + l];
  float S[8];
#pragma unroll
  for (int r = 0; r < 8; ++r) S[r] = 0.0f;
  const float2* pa = PK2A + (size_t)(jc * 256 + w * 64) * NL + l;
  const float* pb = PK2B + (size_t)(jc * 256 + w * 64) * NL + l;
#pragma unroll 4
  for (int jj = 0; jj < 64; ++jj) {
    float2 c01 = pa[(size_t)jj * NL];
    float c2 = pb[(size_t)jj * NL];
#pragma unroll
    for (int r = 0; r < 8; ++r) {
      float lp2 = fmaf(fmaf(zr[r], c01.x, c01.y), zr[r], c2);
      S[r] += __builtin_amdgcn_exp2f(lp2);
    }
  }
  __shared__ float lss[4][8][64];
#pragma unroll
  for (int r = 0; r < 8; ++r) lss[w][r][l] = S[r];
  __syncthreads();
  for (int pp = tid; pp < 512; pp += 256) {
    int r = pp >> 6, ll = pp & 63;
    float Sc = lss[0][r][ll] + lss[1][r][ll] + lss[2][r][ll] + lss[3][r][ll];
    SP[((size_t)jc * NB + (i0 + r)) * NL + ll] = Sc;
  }
}

// K4: per-i: sum 8 j-chunk partials per (i,l) -> log2, sum over l (+64*BVAL),
// LSE-merge the 8 t-chunks -> log_qz; write per-i contribution. 1 wave per i.
__global__ __launch_bounds__(256) void k4_fin(const float* __restrict__ SP,
                                              const float* __restrict__ TPM,
                                              const float* __restrict__ TPS,
                                              float* __restrict__ PERI) {
  int tid = threadIdx.x;
  int w = tid >> 6, l = tid & 63;
  int i = blockIdx.x * 4 + w;
  float S = 0.0f;
#pragma unroll
  for (int s = 0; s < 8; ++s) S += SP[((size_t)s * NB + i) * NL + l];
  float val = __builtin_amdgcn_logf(S);  // log2
  float lqp2 = wredsum(val) + 64.0f * BVAL;
  float tm = (l < 8) ? TPM[i * 8 + l] : -1e30f;
  float ts = (l < 8) ? TPS[i * 8 + l] : 0.0f;
  float Mt = wredmax(tm);
  float St = wredsum(ts * __builtin_amdgcn_exp2f(tm - Mt));
  float lqz2 = Mt + __builtin_amdgcn_logf(St);
  if (l == 0) PERI[i] = lqz2 - lqp2;
}

// K5: final scalar. sum KLP[512], sum PERI[2048].
__global__ __launch_bounds__(256) void k5_out(const float* __restrict__ KLP,
                                              const float* __restrict__ PERI,
                                              float* __restrict__ out) {
  int tid = threadIdx.x;
  float a = 0.0f, b = 0.0f;
  for (int x = tid; x < 512; x += 256) a += KLP[x];
  for (int x = tid; x < 2048; x += 256) b += PERI[x];
  float ra = wredsum(a), rb = wredsum(b);
  __shared__ float sa[4], sb[4];
  if ((tid & 63) == 0) {
    sa[tid >> 6] = ra;
    sb[tid >> 6] = rb;
  }
  __syncthreads();
  if (tid == 0) {
    const float LN2 = 0.6931471805599453f;
    float ka = sa[0] + sa[1] + sa[2] + sa[3];
    float kb = sb[0] + sb[1] + sb[2] + sb[3];
    out[0] = ka + 5.0f * LN2 * kb * (1.0f / (float)NB);
  }
}

extern "C" void kernel_launch(void* const* d_in, const int* in_sizes, int n_in,
                              void* d_out, int out_size, void* d_ws, size_t ws_size,
                              hipStream_t stream) {
  const float* kl = (const float*)d_in[0];
  const float* zm = (const float*)d_in[1];
  const float* zlv = (const float*)d_in[2];
  const float* zs = (const float*)d_in[3];
  float* ws = (float*)d_ws;

  float* PK2A = ws;                 // 2*NE
  float* PK2B = PK2A + 2 * NE;      // NE
  float* A2T = PK2B + NE;           // NE
  float* MA2T = A2T + NE;           // NE
  float* QC2 = MA2T + NE;           // NB
  float* SP = QC2 + NB;             // 8*NE
  float* TPM = SP + 8 * NE;         // NB*8
  float* TPS = TPM + NB * 8;        // NB*8
  float* KLP = TPS + NB * 8;        // 512
  float* PERI = KLP + 512;          // NB     (total ~6.8 MB)

  k1_pre<<<NE / 256, 256, 0, stream>>>(kl, zm, zlv, (float2*)PK2A, PK2B, A2T,
                                       MA2T, QC2, KLP);
  k23<<<dim3(8, NB / 8), 256, 0, stream>>>(zs, A2T, MA2T, QC2,
                                           (const float2*)PK2A, PK2B, TPM, TPS,
                                           SP);
  k4_fin<<<NB / 4, 256, 0, stream>>>(SP, TPM, TPS, PERI);
  k5_out<<<1, 256, 0, stream>>>(KLP, PERI, (float*)d_out);
}

// Round 3
// 129.244 us; speedup vs baseline: 2.2189x; 1.0071x over previous
//
#include <hip/hip_runtime.h>
#include <math.h>

// B=2048, L=64. out = sum(kl) + (BETA-1)*mean_i(log_qz_i - log_qz_product_i)
// lp2[i,j,l] = lp/ln2 = a2*d^2 + b2, d = z_i_l - m_j_l, a2 = -0.5/ln2*exp(-lv) < 0
// Single-pass LSE with constant shift BVAL (valid since lp2 <= b2 << BVAL).
// Horner: lp2 - BVAL = fma(fma(z, a2, c1), z, c0'), c1=-2*a2*m, c0'=a2*m^2+b2-BVAL.
//
// Round-3: k23 is VALU-issue-bound (VALUBusy 72%, HBM 1.5%). Use packed fp32
// (v_pk_fma_f32 / v_pk_mul_f32 / v_pk_add_f32, CDNA3+) to halve the FMA/add
// issue slots by pairing the i-dimension (r). Per-lane pk rounding == fmaf,
// same accumulation order -> bit-identical output. A2T/MA2T merged into one
// interleaved float2 array (halves K2's load instructions).

#define NB 2048
#define NL 64
#define NE (NB * NL)
#define BVAL 12.0f

typedef float f32x2 __attribute__((ext_vector_type(2)));

__device__ __forceinline__ f32x2 pk_fma(f32x2 a, f32x2 b, f32x2 c) {
  f32x2 d;
  asm("v_pk_fma_f32 %0, %1, %2, %3" : "=v"(d) : "v"(a), "v"(b), "v"(c));
  return d;
}
__device__ __forceinline__ f32x2 pk_mul(f32x2 a, f32x2 b) {
  f32x2 d;
  asm("v_pk_mul_f32 %0, %1, %2" : "=v"(d) : "v"(a), "v"(b));
  return d;
}
__device__ __forceinline__ f32x2 pk_add(f32x2 a, f32x2 b) {
  f32x2 d;
  asm("v_pk_add_f32 %0, %1, %2" : "=v"(d) : "v"(a), "v"(b));
  return d;
}

__device__ __forceinline__ float wredsum(float v) {
#pragma unroll
  for (int o = 32; o; o >>= 1) v += __shfl_xor(v, o, 64);
  return v;
}
__device__ __forceinline__ float wredmax(float v) {
#pragma unroll
  for (int o = 32; o; o >>= 1) v = fmaxf(v, __shfl_xor(v, o, 64));
  return v;
}

// K1: packed Horner coeffs (a2,c1 | c0') for the K3 path, interleaved (a2,c1)
// transposed array + qc2 for the K2 path, per-block kl partial sums.
__global__ __launch_bounds__(256) void k1_pre(const float* __restrict__ kl,
                                              const float* __restrict__ zm,
                                              const float* __restrict__ zlv,
                                              float2* __restrict__ PK2A,
                                              float* __restrict__ PK2B,
                                              float2* __restrict__ AM2T,
                                              float* __restrict__ QC2,
                                              float* __restrict__ KLP) {
  const float INVLN2 = 1.4426950408889634f;
  const float LOG2PI = 1.8378770664093453f;
  int tid = threadIdx.x;
  int e = blockIdx.x * 256 + tid;  // < NE
  int j = e >> 6, l = e & 63;
  float lv = zlv[e], m = zm[e];
  float a2 = -0.5f * INVLN2 * __expf(-lv);
  float b2 = -0.5f * INVLN2 * (lv + LOG2PI);
  float c1 = -2.0f * a2 * m;
  float c0 = fmaf(a2 * m, m, b2);  // true a2*m^2 + b2
  PK2A[e] = make_float2(a2, c1);
  PK2B[e] = c0 - BVAL;
  AM2T[l * NB + j] = make_float2(a2, c1);
  float q = wredsum(c0);  // sum_l (a2 m^2 + b2) for this j (one j per wave)
  if (l == 0) QC2[j] = q;
  float ks = wredsum(kl[e]);
  __shared__ float sk[4];
  if (l == 0) sk[tid >> 6] = ks;
  __syncthreads();
  if (tid == 0) KLP[blockIdx.x] = sk[0] + sk[1] + sk[2] + sk[3];
}

// Fused K2+K3 (independent phases, same grid, no cross-block comm).
// grid (8 j-chunks, 256 i-tiles), 256 thr.
// K2 phase: thread = one j, 8 i's (packed as 4 f32x2); dot over l via zsh.
// K3 phase: thread = (wave w, lane l); 64 j's per wave, 8 i's per thread.
// Linear block id = jc + 8*it -> XCD = bid%8 = jc: each XCD streams only its
// own 256KB jc-chunk of PK2 (L2 locality); keep this mapping.
__global__ __launch_bounds__(256) void k23(const float* __restrict__ zs,
                                           const float2* __restrict__ AM2T,
                                           const float* __restrict__ QC2,
                                           const float2* __restrict__ PK2A,
                                           const float* __restrict__ PK2B,
                                           float* __restrict__ TPM,
                                           float* __restrict__ TPS,
                                           float* __restrict__ SP) {
  int jc = blockIdx.x;      // 0..7
  int i0 = blockIdx.y * 8;  // i tile base
  int tid = threadIdx.x;
  int w = tid >> 6, l = tid & 63;
  int j = jc * 256 + tid;

  __shared__ float zsh[64][8];  // [k][r]
  if (tid < 128) {
    int k = tid >> 1, r0 = (tid & 1) * 4;
#pragma unroll
    for (int r = 0; r < 4; ++r) zsh[k][r0 + r] = zs[(i0 + r0 + r) * NL + k];
  }
  __syncthreads();

  // ---------------- K2 phase (packed fp32, same math/order) --------------
  float q = QC2[j];
  f32x2 accp[4];
#pragma unroll
  for (int p = 0; p < 4; ++p) accp[p] = (f32x2){q, q};
  for (int k = 0; k < 64; ++k) {
    float2 am = AM2T[k * NB + j];  // (a2, c1)
    f32x2 av2 = {am.x, am.x}, mv2 = {am.y, am.y};
    const float4* z4 = (const float4*)&zsh[k][0];  // wave-uniform -> broadcast
    float4 za = z4[0], zb = z4[1];
    f32x2 zp[4] = {{za.x, za.y}, {za.z, za.w}, {zb.x, zb.y}, {zb.z, zb.w}};
#pragma unroll
    for (int p = 0; p < 4; ++p) {
      f32x2 zz = pk_mul(zp[p], zp[p]);          // zk*zk   (same rounding)
      accp[p] = pk_fma(zz, av2, accp[p]);       // fmaf(zk*zk, a2, acc)
      accp[p] = pk_fma(zp[p], mv2, accp[p]);    // fmaf(zk,    c1, acc)
    }
  }
  float accv[8];
#pragma unroll
  for (int p = 0; p < 4; ++p) {
    accv[2 * p] = accp[p].x;
    accv[2 * p + 1] = accp[p].y;
  }
  __shared__ float lm[4][8], ls[4][8];
  float Mt[8];
#pragma unroll
  for (int r = 0; r < 8; ++r) {
    float mx = wredmax(accv[r]);
    if (l == 0) lm[w][r] = mx;
  }
  __syncthreads();
#pragma unroll
  for (int r = 0; r < 8; ++r)
    Mt[r] = fmaxf(fmaxf(lm[0][r], lm[1][r]), fmaxf(lm[2][r], lm[3][r]));
#pragma unroll
  for (int r = 0; r < 8; ++r) {
    float ss = wredsum(__builtin_amdgcn_exp2f(accv[r] - Mt[r]));
    if (l == 0) ls[w][r] = ss;
  }
  __syncthreads();
  if (tid == 0) {
#pragma unroll
    for (int r = 0; r < 8; ++r) {
      TPM[(i0 + r) * 8 + jc] = Mt[r];
      TPS[(i0 + r) * 8 + jc] = ls[0][r] + ls[1][r] + ls[2][r] + ls[3][r];
    }
  }

  // ---------------- K3 phase (packed fp32, 12B coeffs, same order) -------
  float zr[8];
#pragma unroll
  for (int r = 0; r < 8; ++r) zr[r] = zs[(i0 + r) * NL + l];
  f32x2 zp2[4];
#pragma unroll
  for (int p = 0; p < 4; ++p) zp2[p] = (f32x2){zr[2 * p], zr[2 * p + 1]};
  f32x2 Sp[4];
#pragma unroll
  for (int p = 0; p < 4; ++p) Sp[p] = (f32x2){0.0f, 0.0f};
  const float2* pa = PK2A + (size_t)(jc * 256 + w * 64) * NL + l;
  const float* pb = PK2B + (size_t)(jc * 256 + w * 64) * NL + l;
#pragma unroll 4
  for (int jj = 0; jj < 64; ++jj) {
    float2 c01 = pa[(size_t)jj * NL];
    float c2 = pb[(size_t)jj * NL];
    f32x2 ab = {c01.x, c01.x}, cb = {c01.y, c01.y}, db = {c2, c2};
#pragma unroll
    for (int p = 0; p < 4; ++p) {
      f32x2 t = pk_fma(zp2[p], ab, cb);   // fmaf(z, a2, c1)
      f32x2 lp = pk_fma(t, zp2[p], db);   // fmaf(t, z, c0')
      f32x2 e = {__builtin_amdgcn_exp2f(lp.x), __builtin_amdgcn_exp2f(lp.y)};
      Sp[p] = pk_add(Sp[p], e);           // S[r] += e, same per-half order
    }
  }
  float S[8];
#pragma unroll
  for (int p = 0; p < 4; ++p) {
    S[2 * p] = Sp[p].x;
    S[2 * p + 1] = Sp[p].y;
  }
  __shared__ float lss[4][8][64];
#pragma unroll
  for (int r = 0; r < 8; ++r) lss[w][r][l] = S[r];
  __syncthreads();
  for (int pp = tid; pp < 512; pp += 256) {
    int r = pp >> 6, ll = pp & 63;
    float Sc = lss[0][r][ll] + lss[1][r][ll] + lss[2][r][ll] + lss[3][r][ll];
    SP[((size_t)jc * NB + (i0 + r)) * NL + ll] = Sc;
  }
}

// K4: per-i: sum 8 j-chunk partials per (i,l) -> log2, sum over l (+64*BVAL),
// LSE-merge the 8 t-chunks -> log_qz; write per-i contribution. 1 wave per i.
__global__ __launch_bounds__(256) void k4_fin(const float* __restrict__ SP,
                                              const float* __restrict__ TPM,
                                              const float* __restrict__ TPS,
                                              float* __restrict__ PERI) {
  int tid = threadIdx.x;
  int w = tid >> 6, l = tid & 63;
  int i = blockIdx.x * 4 + w;
  float S = 0.0f;
#pragma unroll
  for (int s = 0; s < 8; ++s) S += SP[((size_t)s * NB + i) * NL + l];
  float val = __builtin_amdgcn_logf(S);  // log2
  float lqp2 = wredsum(val) + 64.0f * BVAL;
  float tm = (l < 8) ? TPM[i * 8 + l] : -1e30f;
  float ts = (l < 8) ? TPS[i * 8 + l] : 0.0f;
  float Mt = wredmax(tm);
  float St = wredsum(ts * __builtin_amdgcn_exp2f(tm - Mt));
  float lqz2 = Mt + __builtin_amdgcn_logf(St);
  if (l == 0) PERI[i] = lqz2 - lqp2;
}

// K5: final scalar. sum KLP[512], sum PERI[2048].
__global__ __launch_bounds__(256) void k5_out(const float* __restrict__ KLP,
                                              const float* __restrict__ PERI,
                                              float* __restrict__ out) {
  int tid = threadIdx.x;
  float a = 0.0f, b = 0.0f;
  for (int x = tid; x < 512; x += 256) a += KLP[x];
  for (int x = tid; x < 2048; x += 256) b += PERI[x];
  float ra = wredsum(a), rb = wredsum(b);
  __shared__ float sa[4], sb[4];
  if ((tid & 63) == 0) {
    sa[tid >> 6] = ra;
    sb[tid >> 6] = rb;
  }
  __syncthreads();
  if (tid == 0) {
    const float LN2 = 0.6931471805599453f;
    float ka = sa[0] + sa[1] + sa[2] + sa[3];
    float kb = sb[0] + sb[1] + sb[2] + sb[3];
    out[0] = ka + 5.0f * LN2 * kb * (1.0f / (float)NB);
  }
}

extern "C" void kernel_launch(void* const* d_in, const int* in_sizes, int n_in,
                              void* d_out, int out_size, void* d_ws, size_t ws_size,
                              hipStream_t stream) {
  const float* kl = (const float*)d_in[0];
  const float* zm = (const float*)d_in[1];
  const float* zlv = (const float*)d_in[2];
  const float* zs = (const float*)d_in[3];
  float* ws = (float*)d_ws;

  float* PK2A = ws;                 // 2*NE
  float* PK2B = PK2A + 2 * NE;      // NE
  float* AM2T = PK2B + NE;          // 2*NE (interleaved a2,c1 transposed)
  float* QC2 = AM2T + 2 * NE;       // NB
  float* SP = QC2 + NB;             // 8*NE
  float* TPM = SP + 8 * NE;         // NB*8
  float* TPS = TPM + NB * 8;        // NB*8
  float* KLP = TPS + NB * 8;        // 512
  float* PERI = KLP + 512;          // NB     (total ~7.3 MB)

  k1_pre<<<NE / 256, 256, 0, stream>>>(kl, zm, zlv, (float2*)PK2A, PK2B,
                                       (float2*)AM2T, QC2, KLP);
  k23<<<dim3(8, NB / 8), 256, 0, stream>>>(zs, (const float2*)AM2T, QC2,
                                           (const float2*)PK2A, PK2B, TPM, TPS,
                                           SP);
  k4_fin<<<NB / 4, 256, 0, stream>>>(SP, TPM, TPS, PERI);
  k5_out<<<1, 256, 0, stream>>>(KLP, PERI, (float*)d_out);
}